// Round 5
// baseline (179.183 us; speedup 1.0000x reference)
//
#include <hip/hip_runtime.h>
#include <hip/hip_fp16.h>

#define FH 200
#define FW 200
#define FHW 40000
#define FC 256
#define NBIN 49        // 7*7 output bins
#define NSAMP 196      // NBIN * 4 subsamples
#define OHS 66         // out_h [bin][ch] stride in halves = 33 dwords (ODD ->
                       // full-period bank walk; 136 was ==4 mod 32 -> 32-way)

// ---------------------------------------------------------------------------
// Per-sample geometry: weights (pre-multiplied by valid-mask and 0.25 mean
// factor) and 4 bilinear-corner offsets (elements of the chosen layout).
// Matches the JAX reference (aligned coords, clamp-at-edge, valid in [-1,H]).
// ---------------------------------------------------------------------------
__device__ __forceinline__ void compute_sample(const float* __restrict__ roi,
                                               int s, bool nhwc,
                                               float4* wout, int4* oout)
{
    int   b  = (int)roi[0];
    float cw = roi[1] * 0.25f - 0.5f;
    float ch = roi[2] * 0.25f - 0.5f;
    float rw = fmaxf(roi[3] * 0.25f, 1.0f);
    float rh = fmaxf(roi[4] * 0.25f, 1.0f);
    float th = roi[5] * 0.017453292519943295f;   // pi/180
    float ct = cosf(th);
    float st = sinf(th);
    float bin_h = rh / 7.0f;
    float bin_w = rw / 7.0f;

    int bin = s >> 2;
    int sub = s & 3;
    int iy  = sub >> 1;
    int ix  = sub & 1;
    int ph  = bin / 7;
    int pw  = bin - ph * 7;

    float fy = 0.25f + 0.5f * (float)iy;  // frac = {0.25, 0.75}
    float fx = 0.25f + 0.5f * (float)ix;
    float yy = -rh * 0.5f + ((float)ph + fy) * bin_h;
    float xx = -rw * 0.5f + ((float)pw + fx) * bin_w;
    float y  = yy * ct - xx * st + ch;
    float x  = yy * st + xx * ct + cw;

    bool valid = (y >= -1.0f) && (y <= (float)FH) && (x >= -1.0f) && (x <= (float)FW);
    y = fmaxf(y, 0.0f);
    x = fmaxf(x, 0.0f);
    int y0 = (int)floorf(y);
    int x0 = (int)floorf(x);
    bool cy = (y0 >= FH - 1);
    bool cx = (x0 >= FW - 1);
    int ylo = cy ? (FH - 1) : y0;
    int yhi = cy ? (FH - 1) : (y0 + 1);
    int xlo = cx ? (FW - 1) : x0;
    int xhi = cx ? (FW - 1) : (x0 + 1);
    float ly = cy ? 0.0f : (y - (float)y0);
    float lx = cx ? 0.0f : (x - (float)x0);
    float hy = 1.0f - ly;
    float hx = 1.0f - lx;
    float m  = valid ? 0.25f : 0.0f;   // fold valid-mask + mean(4 samples)

    *wout = make_float4(hy * hx * m, hy * lx * m, ly * hx * m, ly * lx * m);

    int bb = b * (FC * FHW);
    int p0 = ylo * FW + xlo;
    int p1 = ylo * FW + xhi;
    int p2 = yhi * FW + xlo;
    int p3 = yhi * FW + xhi;
    if (nhwc)
        *oout = make_int4(bb + p0 * FC, bb + p1 * FC, bb + p2 * FC, bb + p3 * FC);
    else
        *oout = make_int4(bb + p0, bb + p1, bb + p2, bb + p3);
}

__device__ __forceinline__ float fixnum(float v)
{
    return (v == v && v <= 3.402823466e38f && v >= -3.402823466e38f) ? v : 1e-8f;
}

// ---------------------------------------------------------------------------
// NCHW f32 -> NHWC fp16 transpose. Tile = 64 ch x 32 px, block 256.
// grid (FHW/32, FC/64, N). XOR-swizzled LDS per R2/R3.
// ---------------------------------------------------------------------------
__global__ __launch_bounds__(256)
void transpose_f16_kernel(const float* __restrict__ in, __half* __restrict__ out)
{
    __shared__ __align__(16) __half tileT[32][72];   // stride 144 B
    int b   = blockIdx.z;
    int p0  = blockIdx.x * 32;
    int c0  = blockIdx.y * 64;
    int tid = threadIdx.x;

    const float* inb  = in  + (size_t)b * FC * FHW;
    __half*      outb = out + (size_t)b * FHW * FC;

#pragma unroll
    for (int k = 0; k < 2; ++k) {
        int chl = k * 32 + (tid >> 3);       // 0..63 local channel
        int px4 = (tid & 7) * 4;             // 0,4,..,28 local pixel
        float4 v = *(const float4*)(inb + (size_t)(c0 + chl) * FHW + p0 + px4);
        int g   = ((chl >> 3) ^ (px4 >> 2)) & 7;   // swizzled 8-ch group
        int col = (g << 3) | (chl & 7);
        tileT[px4 + 0][col] = __float2half(v.x);
        tileT[px4 + 1][col] = __float2half(v.y);
        tileT[px4 + 2][col] = __float2half(v.z);
        tileT[px4 + 3][col] = __float2half(v.w);
    }
    __syncthreads();

    int p = tid >> 3;                        // 0..31 pixel
    int q = tid & 7;                         // logical 8-ch group
    int g = (q ^ ((p >> 2) & 7));
    uint4 d = *(const uint4*)&tileT[p][g << 3];
    *(uint4*)(outb + (size_t)(p0 + p) * FC + c0 + q * 8) = d;
}

// ---------------------------------------------------------------------------
// Main kernel: 1D grid of 4*ceil(R/8)*8 blocks in XCD-swizzled supergroups of
// 32:  r = (l>>5)*8 + (l&7), quarter q = (l>>3)&3.  With round-robin
// block->XCD dispatch (%8), all 4 channel-quarters of an RoI land on the SAME
// XCD -> each 512 B NHWC pixel row is fetched once per XCD L2, not 4x.
// Block = 256 thr handles 64 channels of one RoI; 8-lane group owns one bin;
// lane owns 8 channels (16 B fp16 load per corner -> 128 B/group).
// Output staged fp16 in LDS [bin][ch] (stride 66 halves, odd-dword ->
// conflict-free gather), dumped with coalesced float4 stores (12544 B,
// line-aligned -> no RMW).  LDS ~12.8 KB.
// NOTE: no min-waves in __launch_bounds__ — R3's (256,5) clamped VGPRs to 48
// and spilled ~290 MB to scratch.
// ---------------------------------------------------------------------------
__global__ __launch_bounds__(256)
void roi_nhwc_f16_kernel(const __half* __restrict__ feat,
                         const float* __restrict__ rois,
                         float* __restrict__ out, int R)
{
    __shared__ float4 s_w[NSAMP];
    __shared__ int4   s_o[NSAMP];
    __shared__ __half out_h[NBIN * OHS];

    int l = blockIdx.x;
    int r = (l >> 5) * 8 + (l & 7);
    int q = (l >> 3) & 3;
    if (r >= R) return;
    int c0  = q * 64;
    int tid = threadIdx.x;

    const float* roi = rois + r * 6;
    if (tid < NSAMP) {
        float4 w; int4 o;
        compute_sample(roi, tid, true, &w, &o);
        s_w[tid] = w;
        s_o[tid] = o;
    }
    __syncthreads();

    int grp   = tid >> 3;        // 0..31 eight-lane group
    int lane8 = tid & 7;
    int ch8   = lane8 * 8;       // local channel offset 0..56

    const __half* fbase = feat + c0 + ch8;

    for (int bin = grp; bin < NBIN; bin += 32) {
        float acc[8];
#pragma unroll
        for (int i = 0; i < 8; ++i) acc[i] = 0.0f;

#pragma unroll
        for (int sub = 0; sub < 4; ++sub) {
            int s = bin * 4 + sub;
            float4 wt = s_w[s];
            int4   o  = s_o[s];
            uint4 u0 = *(const uint4*)(fbase + o.x);
            uint4 u1 = *(const uint4*)(fbase + o.y);
            uint4 u2 = *(const uint4*)(fbase + o.z);
            uint4 u3 = *(const uint4*)(fbase + o.w);
            const __half2* h0 = (const __half2*)&u0;
            const __half2* h1 = (const __half2*)&u1;
            const __half2* h2 = (const __half2*)&u2;
            const __half2* h3 = (const __half2*)&u3;
#pragma unroll
            for (int j = 0; j < 4; ++j) {
                float2 f0 = __half22float2(h0[j]);
                float2 f1 = __half22float2(h1[j]);
                float2 f2 = __half22float2(h2[j]);
                float2 f3 = __half22float2(h3[j]);
                acc[2 * j + 0] += wt.x * f0.x + wt.y * f1.x + wt.z * f2.x + wt.w * f3.x;
                acc[2 * j + 1] += wt.x * f0.y + wt.y * f1.y + wt.z * f2.y + wt.w * f3.y;
            }
        }
        __half2* dst = (__half2*)&out_h[bin * OHS + ch8];
#pragma unroll
        for (int j = 0; j < 4; ++j)
            dst[j] = __floats2half2_rn(acc[2 * j + 0], acc[2 * j + 1]);
    }
    __syncthreads();

    // Dump LDS [bin][ch_local] -> global [ch][bin], coalesced float4 stores.
    float* obase = out + (size_t)r * (FC * NBIN) + (size_t)c0 * NBIN;
    for (int v4 = tid; v4 < (64 * NBIN) / 4; v4 += 256) {
        int f0 = v4 * 4;
        float vals[4];
#pragma unroll
        for (int i = 0; i < 4; ++i) {
            int f = f0 + i;
            int c = f / NBIN;
            int b = f - c * NBIN;
            vals[i] = fixnum(__half2float(out_h[b * OHS + c]));
        }
        *(float4*)(obase + f0) = make_float4(vals[0], vals[1], vals[2], vals[3]);
    }
}

// ---------------------------------------------------------------------------
// Fallback (ws too small): direct NCHW, correct but slow.
// ---------------------------------------------------------------------------
__global__ __launch_bounds__(256)
void roi_nchw_kernel(const float* __restrict__ feat,
                     const float* __restrict__ rois,
                     float* __restrict__ out)
{
    int r   = blockIdx.x;
    int tid = threadIdx.x;

    __shared__ float4 s_w[NSAMP];
    __shared__ int4   s_o[NSAMP];

    const float* roi = rois + r * 6;
    if (tid < NSAMP) {
        float4 w; int4 o;
        compute_sample(roi, tid, false, &w, &o);
        s_w[tid] = w;
        s_o[tid] = o;
    }
    __syncthreads();

    const float* fc = feat + (size_t)tid * FHW;
    float* obase = out + (size_t)r * (FC * NBIN) + (size_t)tid * NBIN;

    for (int bin = 0; bin < NBIN; ++bin) {
        float a = 0.0f;
#pragma unroll
        for (int k = 0; k < 4; ++k) {
            float4 w = s_w[bin * 4 + k];
            int4   o = s_o[bin * 4 + k];
            a += w.x * fc[o.x] + w.y * fc[o.y] + w.z * fc[o.z] + w.w * fc[o.w];
        }
        obase[bin] = fixnum(a);
    }
}

extern "C" void kernel_launch(void* const* d_in, const int* in_sizes, int n_in,
                              void* d_out, int out_size, void* d_ws, size_t ws_size,
                              hipStream_t stream)
{
    const float* feat = (const float*)d_in[0];
    const float* rois = (const float*)d_in[1];
    float* out = (float*)d_out;

    int R = in_sizes[1] / 6;
    int N = in_sizes[0] / (FC * FHW);
    size_t need = (size_t)in_sizes[0] * sizeof(__half);

    if (ws_size >= need) {
        __half* featT = (__half*)d_ws;
        dim3 tg(FHW / 32, FC / 64, N);
        transpose_f16_kernel<<<tg, 256, 0, stream>>>(feat, featT);
        int nblk = ((R + 7) / 8) * 32;   // XCD-swizzled supergroups of 32
        roi_nhwc_f16_kernel<<<nblk, 256, 0, stream>>>(featT, rois, out, R);
    } else {
        roi_nchw_kernel<<<R, 256, 0, stream>>>(feat, rois, out);
    }
}

// Round 6
// 171.854 us; speedup vs baseline: 1.0426x; 1.0426x over previous
//
#include <hip/hip_runtime.h>
#include <hip/hip_fp16.h>

#define FH 200
#define FW 200
#define FHW 40000
#define FC 256
#define NBIN 49        // 7*7 output bins
#define NSAMP 196      // NBIN * 4 subsamples
#define OHS 66         // out_h [bin][ch] stride in halves = 33 dwords (odd ->
                       // full-period bank walk, <=2-way conflicts = free)

// ---------------------------------------------------------------------------
// Per-sample geometry: weights (pre-multiplied by valid-mask and 0.25 mean
// factor) and 4 bilinear-corner offsets (elements of the chosen layout).
// Matches the JAX reference (aligned coords, clamp-at-edge, valid in [-1,H]).
// ---------------------------------------------------------------------------
__device__ __forceinline__ void compute_sample(const float* __restrict__ roi,
                                               int s, bool nhwc,
                                               float4* wout, int4* oout)
{
    int   b  = (int)roi[0];
    float cw = roi[1] * 0.25f - 0.5f;
    float ch = roi[2] * 0.25f - 0.5f;
    float rw = fmaxf(roi[3] * 0.25f, 1.0f);
    float rh = fmaxf(roi[4] * 0.25f, 1.0f);
    float th = roi[5] * 0.017453292519943295f;   // pi/180
    float ct = cosf(th);
    float st = sinf(th);
    float bin_h = rh / 7.0f;
    float bin_w = rw / 7.0f;

    int bin = s >> 2;
    int sub = s & 3;
    int iy  = sub >> 1;
    int ix  = sub & 1;
    int ph  = bin / 7;
    int pw  = bin - ph * 7;

    float fy = 0.25f + 0.5f * (float)iy;  // frac = {0.25, 0.75}
    float fx = 0.25f + 0.5f * (float)ix;
    float yy = -rh * 0.5f + ((float)ph + fy) * bin_h;
    float xx = -rw * 0.5f + ((float)pw + fx) * bin_w;
    float y  = yy * ct - xx * st + ch;
    float x  = yy * st + xx * ct + cw;

    bool valid = (y >= -1.0f) && (y <= (float)FH) && (x >= -1.0f) && (x <= (float)FW);
    y = fmaxf(y, 0.0f);
    x = fmaxf(x, 0.0f);
    int y0 = (int)floorf(y);
    int x0 = (int)floorf(x);
    bool cy = (y0 >= FH - 1);
    bool cx = (x0 >= FW - 1);
    int ylo = cy ? (FH - 1) : y0;
    int yhi = cy ? (FH - 1) : (y0 + 1);
    int xlo = cx ? (FW - 1) : x0;
    int xhi = cx ? (FW - 1) : (x0 + 1);
    float ly = cy ? 0.0f : (y - (float)y0);
    float lx = cx ? 0.0f : (x - (float)x0);
    float hy = 1.0f - ly;
    float hx = 1.0f - lx;
    float m  = valid ? 0.25f : 0.0f;   // fold valid-mask + mean(4 samples)

    *wout = make_float4(hy * hx * m, hy * lx * m, ly * hx * m, ly * lx * m);

    int bb = b * (FC * FHW);
    int p0 = ylo * FW + xlo;
    int p1 = ylo * FW + xhi;
    int p2 = yhi * FW + xlo;
    int p3 = yhi * FW + xhi;
    if (nhwc)
        *oout = make_int4(bb + p0 * FC, bb + p1 * FC, bb + p2 * FC, bb + p3 * FC);
    else
        *oout = make_int4(bb + p0, bb + p1, bb + p2, bb + p3);
}

__device__ __forceinline__ float fixnum(float v)
{
    return (v == v && v <= 3.402823466e38f && v >= -3.402823466e38f) ? v : 1e-8f;
}

// ---------------------------------------------------------------------------
// NCHW f32 -> NHWC fp16 transpose. Tile = 64 ch x 32 px, block 256.
// grid (FHW/32, FC/64, N). XOR-swizzled LDS: phase-1 b16 scatter hits all 32
// banks, phase-2 keeps 16B-aligned ds_read_b128.
// ---------------------------------------------------------------------------
__global__ __launch_bounds__(256)
void transpose_f16_kernel(const float* __restrict__ in, __half* __restrict__ out)
{
    __shared__ __align__(16) __half tileT[32][72];   // stride 144 B
    int b   = blockIdx.z;
    int p0  = blockIdx.x * 32;
    int c0  = blockIdx.y * 64;
    int tid = threadIdx.x;

    const float* inb  = in  + (size_t)b * FC * FHW;
    __half*      outb = out + (size_t)b * FHW * FC;

#pragma unroll
    for (int k = 0; k < 2; ++k) {
        int chl = k * 32 + (tid >> 3);       // 0..63 local channel
        int px4 = (tid & 7) * 4;             // 0,4,..,28 local pixel
        float4 v = *(const float4*)(inb + (size_t)(c0 + chl) * FHW + p0 + px4);
        int g   = ((chl >> 3) ^ (px4 >> 2)) & 7;   // swizzled 8-ch group
        int col = (g << 3) | (chl & 7);
        tileT[px4 + 0][col] = __float2half(v.x);
        tileT[px4 + 1][col] = __float2half(v.y);
        tileT[px4 + 2][col] = __float2half(v.z);
        tileT[px4 + 3][col] = __float2half(v.w);
    }
    __syncthreads();

    int p = tid >> 3;                        // 0..31 pixel
    int q = tid & 7;                         // logical 8-ch group
    int g = (q ^ ((p >> 2) & 7));
    uint4 d = *(const uint4*)&tileT[p][g << 3];
    *(uint4*)(outb + (size_t)(p0 + p) * FC + c0 + q * 8) = d;
}

// ---------------------------------------------------------------------------
// Main kernel: grid (R, 4); block = 256 thr handles 64 channels of one RoI.
// 8-lane group owns one bin; lane owns 8 channels (16 B fp16 load per corner).
// Inner math is pure packed fp16: v_pk_fma_f16 with broadcast half2 weights
// (pre-packed in LDS) -> zero f16->f32 converts, 2 MACs/inst, and the fp16
// accumulator IS the LDS staging format. 16 fp16 roundings ~2e-3 error vs
// 4.66e-2 budget. Output staged fp16 in LDS [bin][ch] (stride 66 halves),
// dumped with coalesced float4 stores (12544 B, line-aligned -> no RMW).
// NOTE: no min-waves in __launch_bounds__ — R3's (256,5) clamped VGPRs to 48
// and spilled ~290 MB to scratch.
// ---------------------------------------------------------------------------
__global__ __launch_bounds__(256)
void roi_nhwc_f16_kernel(const __half* __restrict__ feat,
                         const float* __restrict__ rois,
                         float* __restrict__ out)
{
    __shared__ __align__(16) uint4 s_wh[NSAMP];  // 4 x broadcast-half2 weights
    __shared__ __align__(16) int4  s_o[NSAMP];
    __shared__ __half out_h[NBIN * OHS];

    int r   = blockIdx.x;
    int c0  = blockIdx.y * 64;    // channel quarter
    int tid = threadIdx.x;

    const float* roi = rois + r * 6;
    if (tid < NSAMP) {
        float4 w; int4 o;
        compute_sample(roi, tid, true, &w, &o);
        __half2 wh[4];
        wh[0] = __half2half2(__float2half(w.x));
        wh[1] = __half2half2(__float2half(w.y));
        wh[2] = __half2half2(__float2half(w.z));
        wh[3] = __half2half2(__float2half(w.w));
        s_wh[tid] = *(const uint4*)wh;
        s_o[tid]  = o;
    }
    __syncthreads();

    int grp   = tid >> 3;        // 0..31 eight-lane group
    int lane8 = tid & 7;
    int ch8   = lane8 * 8;       // local channel offset 0..56

    const __half* fbase = feat + c0 + ch8;

    for (int bin = grp; bin < NBIN; bin += 32) {
        __half2 acc[4];
#pragma unroll
        for (int j = 0; j < 4; ++j) acc[j] = __half2half2(__float2half(0.0f));

#pragma unroll
        for (int sub = 0; sub < 4; ++sub) {
            int s = bin * 4 + sub;
            uint4 whu = s_wh[s];
            const __half2* wh = (const __half2*)&whu;
            int4 o = s_o[s];
            uint4 u0 = *(const uint4*)(fbase + o.x);
            uint4 u1 = *(const uint4*)(fbase + o.y);
            uint4 u2 = *(const uint4*)(fbase + o.z);
            uint4 u3 = *(const uint4*)(fbase + o.w);
            const __half2* h0 = (const __half2*)&u0;
            const __half2* h1 = (const __half2*)&u1;
            const __half2* h2 = (const __half2*)&u2;
            const __half2* h3 = (const __half2*)&u3;
#pragma unroll
            for (int j = 0; j < 4; ++j) {
                acc[j] = __hfma2(wh[0], h0[j], acc[j]);
                acc[j] = __hfma2(wh[1], h1[j], acc[j]);
                acc[j] = __hfma2(wh[2], h2[j], acc[j]);
                acc[j] = __hfma2(wh[3], h3[j], acc[j]);
            }
        }
        __half2* dst = (__half2*)&out_h[bin * OHS + ch8];
#pragma unroll
        for (int j = 0; j < 4; ++j) dst[j] = acc[j];
    }
    __syncthreads();

    // Dump LDS [bin][ch_local] -> global [ch][bin], coalesced float4 stores.
    float* obase = out + (size_t)r * (FC * NBIN) + (size_t)c0 * NBIN;
    for (int v4 = tid; v4 < (64 * NBIN) / 4; v4 += 256) {
        int f0 = v4 * 4;
        float vals[4];
#pragma unroll
        for (int i = 0; i < 4; ++i) {
            int f = f0 + i;
            int c = f / NBIN;
            int b = f - c * NBIN;
            vals[i] = fixnum(__half2float(out_h[b * OHS + c]));
        }
        *(float4*)(obase + f0) = make_float4(vals[0], vals[1], vals[2], vals[3]);
    }
}

// ---------------------------------------------------------------------------
// Fallback (ws too small): direct NCHW, correct but slow.
// ---------------------------------------------------------------------------
__global__ __launch_bounds__(256)
void roi_nchw_kernel(const float* __restrict__ feat,
                     const float* __restrict__ rois,
                     float* __restrict__ out)
{
    int r   = blockIdx.x;
    int tid = threadIdx.x;

    __shared__ float4 s_w[NSAMP];
    __shared__ int4   s_o[NSAMP];

    const float* roi = rois + r * 6;
    if (tid < NSAMP) {
        float4 w; int4 o;
        compute_sample(roi, tid, false, &w, &o);
        s_w[tid] = w;
        s_o[tid] = o;
    }
    __syncthreads();

    const float* fc = feat + (size_t)tid * FHW;
    float* obase = out + (size_t)r * (FC * NBIN) + (size_t)tid * NBIN;

    for (int bin = 0; bin < NBIN; ++bin) {
        float a = 0.0f;
#pragma unroll
        for (int k = 0; k < 4; ++k) {
            float4 w = s_w[bin * 4 + k];
            int4   o = s_o[bin * 4 + k];
            a += w.x * fc[o.x] + w.y * fc[o.y] + w.z * fc[o.z] + w.w * fc[o.w];
        }
        obase[bin] = fixnum(a);
    }
}

extern "C" void kernel_launch(void* const* d_in, const int* in_sizes, int n_in,
                              void* d_out, int out_size, void* d_ws, size_t ws_size,
                              hipStream_t stream)
{
    const float* feat = (const float*)d_in[0];
    const float* rois = (const float*)d_in[1];
    float* out = (float*)d_out;

    int R = in_sizes[1] / 6;
    int N = in_sizes[0] / (FC * FHW);
    size_t need = (size_t)in_sizes[0] * sizeof(__half);

    if (ws_size >= need) {
        __half* featT = (__half*)d_ws;
        dim3 tg(FHW / 32, FC / 64, N);
        transpose_f16_kernel<<<tg, 256, 0, stream>>>(feat, featT);
        dim3 g(R, 4, 1);
        roi_nhwc_f16_kernel<<<g, 256, 0, stream>>>(featT, rois, out);
    } else {
        roi_nchw_kernel<<<R, 256, 0, stream>>>(feat, rois, out);
    }
}

// Round 7
// 170.727 us; speedup vs baseline: 1.0495x; 1.0066x over previous
//
#include <hip/hip_runtime.h>
#include <hip/hip_fp16.h>

#define FH 200
#define FW 200
#define FHW 40000
#define FC 256
#define NBIN 49        // 7*7 output bins
#define NSAMP 196      // NBIN * 4 subsamples
#define OHS 66         // out_h [bin][ch] stride in halves = 33 dwords (odd ->
                       // full-period bank walk, <=2-way conflicts = free)

// ---------------------------------------------------------------------------
// Per-sample geometry: weights (pre-multiplied by valid-mask and 0.25 mean
// factor) and 4 bilinear-corner offsets (elements of the chosen layout).
// Matches the JAX reference (aligned coords, clamp-at-edge, valid in [-1,H]).
// ---------------------------------------------------------------------------
__device__ __forceinline__ void compute_sample(const float* __restrict__ roi,
                                               int s, bool nhwc,
                                               float4* wout, int4* oout)
{
    int   b  = (int)roi[0];
    float cw = roi[1] * 0.25f - 0.5f;
    float ch = roi[2] * 0.25f - 0.5f;
    float rw = fmaxf(roi[3] * 0.25f, 1.0f);
    float rh = fmaxf(roi[4] * 0.25f, 1.0f);
    float th = roi[5] * 0.017453292519943295f;   // pi/180
    float ct = cosf(th);
    float st = sinf(th);
    float bin_h = rh / 7.0f;
    float bin_w = rw / 7.0f;

    int bin = s >> 2;
    int sub = s & 3;
    int iy  = sub >> 1;
    int ix  = sub & 1;
    int ph  = bin / 7;
    int pw  = bin - ph * 7;

    float fy = 0.25f + 0.5f * (float)iy;  // frac = {0.25, 0.75}
    float fx = 0.25f + 0.5f * (float)ix;
    float yy = -rh * 0.5f + ((float)ph + fy) * bin_h;
    float xx = -rw * 0.5f + ((float)pw + fx) * bin_w;
    float y  = yy * ct - xx * st + ch;
    float x  = yy * st + xx * ct + cw;

    bool valid = (y >= -1.0f) && (y <= (float)FH) && (x >= -1.0f) && (x <= (float)FW);
    y = fmaxf(y, 0.0f);
    x = fmaxf(x, 0.0f);
    int y0 = (int)floorf(y);
    int x0 = (int)floorf(x);
    bool cy = (y0 >= FH - 1);
    bool cx = (x0 >= FW - 1);
    int ylo = cy ? (FH - 1) : y0;
    int yhi = cy ? (FH - 1) : (y0 + 1);
    int xlo = cx ? (FW - 1) : x0;
    int xhi = cx ? (FW - 1) : (x0 + 1);
    float ly = cy ? 0.0f : (y - (float)y0);
    float lx = cx ? 0.0f : (x - (float)x0);
    float hy = 1.0f - ly;
    float hx = 1.0f - lx;
    float m  = valid ? 0.25f : 0.0f;   // fold valid-mask + mean(4 samples)

    *wout = make_float4(hy * hx * m, hy * lx * m, ly * hx * m, ly * lx * m);

    int bb = b * (FC * FHW);
    int p0 = ylo * FW + xlo;
    int p1 = ylo * FW + xhi;
    int p2 = yhi * FW + xlo;
    int p3 = yhi * FW + xhi;
    if (nhwc)
        *oout = make_int4(bb + p0 * FC, bb + p1 * FC, bb + p2 * FC, bb + p3 * FC);
    else
        *oout = make_int4(bb + p0, bb + p1, bb + p2, bb + p3);
}

__device__ __forceinline__ float fixnum(float v)
{
    return (v == v && v <= 3.402823466e38f && v >= -3.402823466e38f) ? v : 1e-8f;
}

// ---------------------------------------------------------------------------
// NCHW f32 -> NHWC fp16 transpose. Tile = 64 ch x 32 px, block 256.
// grid (FHW/32, FC/64, N). XOR-swizzled LDS: phase-1 b16 scatter hits all 32
// banks, phase-2 keeps 16B-aligned ds_read_b128.
// ---------------------------------------------------------------------------
__global__ __launch_bounds__(256)
void transpose_f16_kernel(const float* __restrict__ in, __half* __restrict__ out)
{
    __shared__ __align__(16) __half tileT[32][72];   // stride 144 B
    int b   = blockIdx.z;
    int p0  = blockIdx.x * 32;
    int c0  = blockIdx.y * 64;
    int tid = threadIdx.x;

    const float* inb  = in  + (size_t)b * FC * FHW;
    __half*      outb = out + (size_t)b * FHW * FC;

#pragma unroll
    for (int k = 0; k < 2; ++k) {
        int chl = k * 32 + (tid >> 3);       // 0..63 local channel
        int px4 = (tid & 7) * 4;             // 0,4,..,28 local pixel
        float4 v = *(const float4*)(inb + (size_t)(c0 + chl) * FHW + p0 + px4);
        int g   = ((chl >> 3) ^ (px4 >> 2)) & 7;   // swizzled 8-ch group
        int col = (g << 3) | (chl & 7);
        tileT[px4 + 0][col] = __float2half(v.x);
        tileT[px4 + 1][col] = __float2half(v.y);
        tileT[px4 + 2][col] = __float2half(v.z);
        tileT[px4 + 3][col] = __float2half(v.w);
    }
    __syncthreads();

    int p = tid >> 3;                        // 0..31 pixel
    int q = tid & 7;                         // logical 8-ch group
    int g = (q ^ ((p >> 2) & 7));
    uint4 d = *(const uint4*)&tileT[p][g << 3];
    *(uint4*)(outb + (size_t)(p0 + p) * FC + c0 + q * 8) = d;
}

// ---------------------------------------------------------------------------
// Main kernel: grid (R, 4); block = 256 thr handles 64 channels of one RoI.
// 8-lane group owns bins {grp, grp+32}; lane owns 8 channels (16 B fp16 load
// per corner). BOTH bins' 16 loads are issued back-to-back before either is
// consumed: in-order vmcnt keeps bin-B's loads in flight while bin-A's
// packed-fp16 FMAs run -> ~2x memory-level parallelism vs the R6 sequential
// loop (trip count was lane-dependent so the compiler couldn't unroll it).
// Inner math is pure v_pk_fma_f16 with broadcast half2 weights (zero cvts;
// fp16 acc IS the staging format; ~2e-3 err vs 4.66e-2 budget).
// Output staged fp16 in LDS [bin][ch] (stride 66 halves), dumped with
// coalesced float4 stores (12544 B, line-aligned -> no RMW).
// NOTE: no min-waves in __launch_bounds__ — R3's (256,5) clamped VGPRs to 48
// and spilled ~290 MB to scratch. VGPR here is ~150 by design (32 uint4 load
// temps); if WRITE_SIZE grows past 49 MB it's spilling -> revert.
// ---------------------------------------------------------------------------
__global__ __launch_bounds__(256)
void roi_nhwc_f16_kernel(const __half* __restrict__ feat,
                         const float* __restrict__ rois,
                         float* __restrict__ out)
{
    __shared__ __align__(16) uint4 s_wh[NSAMP];  // 4 x broadcast-half2 weights
    __shared__ __align__(16) int4  s_o[NSAMP];
    __shared__ __half out_h[NBIN * OHS];

    int r   = blockIdx.x;
    int c0  = blockIdx.y * 64;    // channel quarter
    int tid = threadIdx.x;

    const float* roi = rois + r * 6;
    if (tid < NSAMP) {
        float4 w; int4 o;
        compute_sample(roi, tid, true, &w, &o);
        __half2 wh[4];
        wh[0] = __half2half2(__float2half(w.x));
        wh[1] = __half2half2(__float2half(w.y));
        wh[2] = __half2half2(__float2half(w.z));
        wh[3] = __half2half2(__float2half(w.w));
        s_wh[tid] = *(const uint4*)wh;
        s_o[tid]  = o;
    }
    __syncthreads();

    int grp   = tid >> 3;        // 0..31 eight-lane group
    int lane8 = tid & 7;
    int ch8   = lane8 * 8;       // local channel offset 0..56

    const __half* fbase = feat + c0 + ch8;

    int binA = grp;              // always < NBIN (grp <= 31)
    int binB = grp + 32;         // valid for grp < 17
    bool hasB = (binB < NBIN);   // uniform within each 8-lane group

    // ---- issue ALL loads first: 16 for binA, then 16 for binB -------------
    uint4 la[16], lb[16];
#pragma unroll
    for (int sub = 0; sub < 4; ++sub) {
        int4 o = s_o[binA * 4 + sub];
        la[sub * 4 + 0] = *(const uint4*)(fbase + o.x);
        la[sub * 4 + 1] = *(const uint4*)(fbase + o.y);
        la[sub * 4 + 2] = *(const uint4*)(fbase + o.z);
        la[sub * 4 + 3] = *(const uint4*)(fbase + o.w);
    }
    if (hasB) {
#pragma unroll
        for (int sub = 0; sub < 4; ++sub) {
            int4 o = s_o[binB * 4 + sub];
            lb[sub * 4 + 0] = *(const uint4*)(fbase + o.x);
            lb[sub * 4 + 1] = *(const uint4*)(fbase + o.y);
            lb[sub * 4 + 2] = *(const uint4*)(fbase + o.z);
            lb[sub * 4 + 3] = *(const uint4*)(fbase + o.w);
        }
    }

    // ---- consume binA (binB's loads stay outstanding) ---------------------
    {
        __half2 acc[4];
#pragma unroll
        for (int j = 0; j < 4; ++j) acc[j] = __half2half2(__float2half(0.0f));
#pragma unroll
        for (int sub = 0; sub < 4; ++sub) {
            uint4 whu = s_wh[binA * 4 + sub];
            const __half2* wh = (const __half2*)&whu;
#pragma unroll
            for (int c = 0; c < 4; ++c) {
                const __half2* h = (const __half2*)&la[sub * 4 + c];
#pragma unroll
                for (int j = 0; j < 4; ++j)
                    acc[j] = __hfma2(wh[c], h[j], acc[j]);
            }
        }
        __half2* dst = (__half2*)&out_h[binA * OHS + ch8];
#pragma unroll
        for (int j = 0; j < 4; ++j) dst[j] = acc[j];
    }

    // ---- consume binB -----------------------------------------------------
    if (hasB) {
        __half2 acc[4];
#pragma unroll
        for (int j = 0; j < 4; ++j) acc[j] = __half2half2(__float2half(0.0f));
#pragma unroll
        for (int sub = 0; sub < 4; ++sub) {
            uint4 whu = s_wh[binB * 4 + sub];
            const __half2* wh = (const __half2*)&whu;
#pragma unroll
            for (int c = 0; c < 4; ++c) {
                const __half2* h = (const __half2*)&lb[sub * 4 + c];
#pragma unroll
                for (int j = 0; j < 4; ++j)
                    acc[j] = __hfma2(wh[c], h[j], acc[j]);
            }
        }
        __half2* dst = (__half2*)&out_h[binB * OHS + ch8];
#pragma unroll
        for (int j = 0; j < 4; ++j) dst[j] = acc[j];
    }
    __syncthreads();

    // Dump LDS [bin][ch_local] -> global [ch][bin], coalesced float4 stores.
    float* obase = out + (size_t)r * (FC * NBIN) + (size_t)c0 * NBIN;
    for (int v4 = tid; v4 < (64 * NBIN) / 4; v4 += 256) {
        int f0 = v4 * 4;
        float vals[4];
#pragma unroll
        for (int i = 0; i < 4; ++i) {
            int f = f0 + i;
            int c = f / NBIN;
            int b = f - c * NBIN;
            vals[i] = fixnum(__half2float(out_h[b * OHS + c]));
        }
        *(float4*)(obase + f0) = make_float4(vals[0], vals[1], vals[2], vals[3]);
    }
}

// ---------------------------------------------------------------------------
// Fallback (ws too small): direct NCHW, correct but slow.
// ---------------------------------------------------------------------------
__global__ __launch_bounds__(256)
void roi_nchw_kernel(const float* __restrict__ feat,
                     const float* __restrict__ rois,
                     float* __restrict__ out)
{
    int r   = blockIdx.x;
    int tid = threadIdx.x;

    __shared__ float4 s_w[NSAMP];
    __shared__ int4   s_o[NSAMP];

    const float* roi = rois + r * 6;
    if (tid < NSAMP) {
        float4 w; int4 o;
        compute_sample(roi, tid, false, &w, &o);
        s_w[tid] = w;
        s_o[tid] = o;
    }
    __syncthreads();

    const float* fc = feat + (size_t)tid * FHW;
    float* obase = out + (size_t)r * (FC * NBIN) + (size_t)tid * NBIN;

    for (int bin = 0; bin < NBIN; ++bin) {
        float a = 0.0f;
#pragma unroll
        for (int k = 0; k < 4; ++k) {
            float4 w = s_w[bin * 4 + k];
            int4   o = s_o[bin * 4 + k];
            a += w.x * fc[o.x] + w.y * fc[o.y] + w.z * fc[o.z] + w.w * fc[o.w];
        }
        obase[bin] = fixnum(a);
    }
}

extern "C" void kernel_launch(void* const* d_in, const int* in_sizes, int n_in,
                              void* d_out, int out_size, void* d_ws, size_t ws_size,
                              hipStream_t stream)
{
    const float* feat = (const float*)d_in[0];
    const float* rois = (const float*)d_in[1];
    float* out = (float*)d_out;

    int R = in_sizes[1] / 6;
    int N = in_sizes[0] / (FC * FHW);
    size_t need = (size_t)in_sizes[0] * sizeof(__half);

    if (ws_size >= need) {
        __half* featT = (__half*)d_ws;
        dim3 tg(FHW / 32, FC / 64, N);
        transpose_f16_kernel<<<tg, 256, 0, stream>>>(feat, featT);
        dim3 g(R, 4, 1);
        roi_nhwc_f16_kernel<<<g, 256, 0, stream>>>(featT, rois, out);
    } else {
        roi_nchw_kernel<<<R, 256, 0, stream>>>(feat, rois, out);
    }
}